// Round 4
// baseline (548.264 us; speedup 1.0000x reference)
//
#include <hip/hip_runtime.h>
#include <stdint.h>

#define NR 8192
#define DD 128

typedef __attribute__((ext_vector_type(8))) short bf16x8;
typedef __attribute__((ext_vector_type(4))) float f32x4;

#ifdef __has_builtin
#if __has_builtin(__builtin_amdgcn_exp2f)
#define EXP2F __builtin_amdgcn_exp2f
#endif
#endif
#ifndef EXP2F
#define EXP2F exp2f
#endif

// exp(10*x) == exp2(x * 10/ln2).  The 10/ln2 is folded into the stored bf16:
// nb = round_bf16( sqrt(10/ln2) * normalized ), so every pairwise product
// (MFMA dot, p0 elementwise, diag) is already the exp2 argument.
#define SQK 3.79828255f   // sqrt(10/ln2)

__device__ __forceinline__ uint16_t f2bf_rne(float f) {
  uint32_t u = __float_as_uint(f);
  u += 0x7FFFu + ((u >> 16) & 1u);
  return (uint16_t)(u >> 16);
}
__device__ __forceinline__ float bf2f(uint16_t h) {
  return __uint_as_float(((uint32_t)h) << 16);
}

// ---------------------------------------------------------------------------
// K1: row L2-normalize (fp32 math), emit bf16 copies scaled by SQK, plus
// diag = sum(stored^2). Also zeroes the 6 row-sum arrays and d_out.
// ---------------------------------------------------------------------------
__global__ __launch_bounds__(256) void k_normalize(
    const float* __restrict__ u1, const float* __restrict__ u2,
    const float* __restrict__ i1, const float* __restrict__ i2,
    uint16_t* __restrict__ nb, float* __restrict__ diag,
    float* __restrict__ sums, float* __restrict__ out)
{
  int tid = threadIdx.x;
  int gid = blockIdx.x * 256 + tid;
  if (gid < 6 * NR) sums[gid] = 0.0f;
  if (gid == 0) out[0] = 0.0f;

  int w = tid >> 6, lane = tid & 63;
  int rowId = blockIdx.x * 4 + w;            // 0..32767
  int mi = rowId >> 13, r = rowId & (NR - 1);
  const float* src = (mi == 0) ? u1 : (mi == 1) ? u2 : (mi == 2) ? i1 : i2;
  const float2 v = *(const float2*)(src + (size_t)r * DD + lane * 2);
  float ss = v.x * v.x + v.y * v.y;
#pragma unroll
  for (int off = 32; off >= 1; off >>= 1) ss += __shfl_xor(ss, off, 64);
  float sc = SQK / fmaxf(sqrtf(ss), 1e-12f);
  uint16_t b0 = f2bf_rne(v.x * sc);
  uint16_t b1 = f2bf_rne(v.y * sc);
  uint16_t* dst = nb + (size_t)mi * NR * DD + (size_t)r * DD + lane * 2;
  *(uint32_t*)dst = (uint32_t)b0 | ((uint32_t)b1 << 16);
  float f0 = bf2f(b0), f1 = bf2f(b1);
  float dd = f0 * f0 + f1 * f1;
#pragma unroll
  for (int off = 32; off >= 1; off >>= 1) dd += __shfl_xor(dd, off, 64);
  if (lane == 0) diag[rowId] = dd;
}

// ---------------------------------------------------------------------------
// K2: Gram row-sums with SYMMETRY: s11/s22 Grams are symmetric, so only the
// upper-triangular 256x256 blocks are computed; off-diagonal blocks emit
// row-sums AND col-sums (col-sum j == transposed row-sum).  Work: 6 full
// Grams -> 2 full (cross s12) + 4 triangles = 4.06 equivalents (-32%).
// Per block: 4 waves x 64 rows (MR=4); 4 staged 64-col tiles, 2-phase
// double-buffered LDS pipeline, one barrier per tile.
// grid = 2*1024 (cross) + 4*528 (triangle) = 4160 blocks, XCD-chunk swizzle.
// ---------------------------------------------------------------------------
__global__ __launch_bounds__(256, 4) void k_gram(
    const uint16_t* __restrict__ nb, float* __restrict__ sums)
{
  __shared__ alignas(16) uint16_t ldsB[2][64 * DD];   // 2 x 16 KB

  // bijective XCD-chunk swizzle: 4160 = 8 * 520
  int bid = (blockIdx.x & 7) * 520 + (blockIdx.x >> 3);

  int job, rb, cb;
  if (bid < 2048) {                    // cross jobs: full 32x32 block grid
    job = (bid >= 1024) ? 3 : 0;
    int r = bid & 1023;
    rb = r >> 5;
    cb = r & 31;
  } else {                             // symmetric jobs: upper triangle
    int s = bid - 2048;
    int grp = s / 528;                 // 0..3
    int idx = s - grp * 528;
    const int sjob[4] = {1, 2, 4, 5};
    job = sjob[grp];
    // triangular decode: C(r) = r*(65-r)/2 blocks before row r
    int r = (int)((65.0f - sqrtf(4225.0f - 8.0f * (float)idx)) * 0.5f);
    r = (r < 0) ? 0 : (r > 31 ? 31 : r);
    while (r > 0 && (r * (65 - r)) / 2 > idx) --r;
    while (r < 31 && ((r + 1) * (64 - r)) / 2 <= idx) ++r;
    rb = r;
    cb = r + (idx - (r * (65 - r)) / 2);
  }
  bool needCol = (job != 0 && job != 3) && (rb != cb);

  // job -> (A matrix, B matrix, output slot): 0:(u1,u2)->s12u 1:(u1,u1)->s11u
  // 2:(u2,u2)->s22u 3:(i1,i2)->s12i 4:(i1,i1)->s11i 5:(i2,i2)->s22i
  const int ja[6] = {0, 0, 1, 2, 2, 3};
  const int jb[6] = {1, 0, 1, 3, 2, 3};
  const uint16_t* A = nb + (size_t)ja[job] * NR * DD;
  const uint16_t* B = nb + (size_t)jb[job] * NR * DD;
  float* out = sums + job * NR;

  int tid = threadIdx.x, w = tid >> 6, lane = tid & 63;
  int l15 = lane & 15, lg = lane >> 4;
  int rowBase = rb * 256 + w * 64;
  int colBase = cb * 256;

  const char* Bb = (const char*)B;
  char* buf0 = (char*)&ldsB[0][0];
  char* buf1 = (char*)&ldsB[1][0];

  // stage one 64-col B tile (16KB): linear LDS dest, inverse-swizzled global
  // source (rule #21)
#define STAGE(dst, jt)                                                        \
  {                                                                           \
    const char* tbase = Bb + (size_t)(colBase + (jt) * 64) * 256;             \
    _Pragma("unroll")                                                         \
    for (int it = 0; it < 4; ++it) {                                          \
      int dbase = w * 4096 + it * 1024;                                       \
      int doff = dbase + lane * 16;                                           \
      int soff = doff ^ (((doff >> 8) & 7) << 4);                             \
      __builtin_amdgcn_global_load_lds(                                       \
          (const __attribute__((address_space(1))) void*)(tbase + soff),      \
          (__attribute__((address_space(3))) void*)((dst) + dbase),           \
          16, 0, 0);                                                          \
    }                                                                         \
  }

  STAGE(buf0, 0);          // prologue; A-frag loads fly under it

  bf16x8 af[4][4];
#pragma unroll
  for (int m = 0; m < 4; ++m) {
    const uint16_t* ap = A + (size_t)(rowBase + m * 16 + l15) * DD + lg * 8;
#pragma unroll
    for (int ks = 0; ks < 4; ++ks)
      af[m][ks] = *(const bf16x8*)(ap + ks * 32);
  }

  float racc[4][4];
#pragma unroll
  for (int m = 0; m < 4; ++m)
#pragma unroll
    for (int j = 0; j < 4; ++j) racc[m][j] = 0.0f;

  __syncthreads();   // tile 0 staged (implicit vmcnt(0) drain)

  for (int jt = 0; jt < 4; ++jt) {
    char* curb = (jt & 1) ? buf1 : buf0;
    char* nxtb = (jt & 1) ? buf0 : buf1;
    if (jt < 3) STAGE(nxtb, jt + 1);   // in-flight under compute

    if (needCol) {
      float csum[4];
#pragma unroll
      for (int c = 0; c < 4; ++c) {
        int r = c * 16 + l15;
        int rbyte = r * 256;
        int swz = (r & 7) << 4;
        bf16x8 bfr[4];
#pragma unroll
        for (int ks = 0; ks < 4; ++ks) {
          int L = rbyte + ks * 64 + lg * 16;
          bfr[ks] = *(const bf16x8*)(curb + (L ^ swz));
        }
        float cacc = 0.0f;
#pragma unroll
        for (int m = 0; m < 4; ++m) {
          f32x4 acc = {0.0f, 0.0f, 0.0f, 0.0f};
#pragma unroll
          for (int ks = 0; ks < 4; ++ks)
            acc = __builtin_amdgcn_mfma_f32_16x16x32_bf16(af[m][ks], bfr[ks], acc, 0, 0, 0);
#pragma unroll
          for (int j = 0; j < 4; ++j) {
            float v = EXP2F(acc[j]);
            racc[m][j] += v;         // row (rowBase+m*16+lg*4+j)
            cacc += v;               // col (colBase+jt*64+c*16+l15)
          }
        }
        csum[c] = cacc;
      }
      // col-sums: reduce over lg (rows), one atomic per col
#pragma unroll
      for (int c = 0; c < 4; ++c) {
        float v = csum[c];
        v += __shfl_xor(v, 16, 64);
        v += __shfl_xor(v, 32, 64);
        if (lg == 0) atomicAdd(&out[colBase + jt * 64 + c * 16 + l15], v);
      }
    } else {
#pragma unroll
      for (int c = 0; c < 4; ++c) {
        int r = c * 16 + l15;
        int rbyte = r * 256;
        int swz = (r & 7) << 4;
        bf16x8 bfr[4];
#pragma unroll
        for (int ks = 0; ks < 4; ++ks) {
          int L = rbyte + ks * 64 + lg * 16;
          bfr[ks] = *(const bf16x8*)(curb + (L ^ swz));
        }
#pragma unroll
        for (int m = 0; m < 4; ++m) {
          f32x4 acc = {0.0f, 0.0f, 0.0f, 0.0f};
#pragma unroll
          for (int ks = 0; ks < 4; ++ks)
            acc = __builtin_amdgcn_mfma_f32_16x16x32_bf16(af[m][ks], bfr[ks], acc, 0, 0, 0);
#pragma unroll
          for (int j = 0; j < 4; ++j)
            racc[m][j] += EXP2F(acc[j]);
        }
      }
    }
    if (jt < 3) __syncthreads();       // next tile staged; cur reusable
  }

  // row-sums: reduce over the 16 lanes (cols) in each lg group
#pragma unroll
  for (int off = 1; off < 16; off <<= 1)
#pragma unroll
    for (int m = 0; m < 4; ++m)
#pragma unroll
      for (int j = 0; j < 4; ++j)
        racc[m][j] += __shfl_xor(racc[m][j], off, 64);

  if (l15 == 0) {
#pragma unroll
    for (int m = 0; m < 4; ++m)
#pragma unroll
      for (int j = 0; j < 4; ++j)
        atomicAdd(&out[rowBase + m * 16 + lg * 4 + j], racc[m][j]);
  }
#undef STAGE
}

// ---------------------------------------------------------------------------
// K3: finalize.  16 rows per wave, one atomic per BLOCK (256 total).
// loss += log(s12+s11+p0) + log(s12+s22+p0) - 2*log(p0);  out = loss/4.
// ---------------------------------------------------------------------------
__global__ __launch_bounds__(256) void k_finalize(
    const uint16_t* __restrict__ nb, const float* __restrict__ diag,
    const float* __restrict__ sums, float* __restrict__ out)
{
  __shared__ float part[4];
  int tid = threadIdx.x, w = tid >> 6, lane = tid & 63;
  int waveId = blockIdx.x * 4 + w;        // 0..1023
  float local = 0.0f;

  for (int i = 0; i < 16; ++i) {
    int rowId = waveId * 16 + i;          // 0..16383
    int p = rowId >> 13, r = rowId & (NR - 1);
    const uint16_t* n1 = nb + (size_t)(2 * p) * NR * DD + (size_t)r * DD;
    const uint16_t* n2 = n1 + (size_t)NR * DD;
    uint32_t a = *(const uint32_t*)(n1 + lane * 2);
    uint32_t b = *(const uint32_t*)(n2 + lane * 2);
    float a0 = bf2f((uint16_t)(a & 0xFFFFu)), a1 = bf2f((uint16_t)(a >> 16));
    float b0 = bf2f((uint16_t)(b & 0xFFFFu)), b1 = bf2f((uint16_t)(b >> 16));
    // values pre-scaled by SQK: product is already the exp2 argument
    float p0 = EXP2F(a0 * b0) + EXP2F(a1 * b1);
#pragma unroll
    for (int off = 32; off >= 1; off >>= 1) p0 += __shfl_xor(p0, off, 64);

    if (lane == 0) {
      const float* s12v = sums + (3 * p) * NR;
      const float* s11v = sums + (3 * p + 1) * NR;
      const float* s22v = sums + (3 * p + 2) * NR;
      float e1 = EXP2F(diag[(2 * p) * NR + r]);
      float e2 = EXP2F(diag[(2 * p + 1) * NR + r]);
      float s12 = s12v[r];
      float S1 = s12 + (s11v[r] - e1) + p0;
      float S2 = s12 + (s22v[r] - e2) + p0;
      local += logf(S1) + logf(S2) - 2.0f * logf(p0);
    }
  }
  if (lane == 0) part[w] = local;
  __syncthreads();
  if (tid == 0) {
    float t = part[0] + part[1] + part[2] + part[3];
    atomicAdd(out, 0.25f * t);
  }
}

// ---------------------------------------------------------------------------
extern "C" void kernel_launch(void* const* d_in, const int* in_sizes, int n_in,
                              void* d_out, int out_size, void* d_ws, size_t ws_size,
                              hipStream_t stream) {
  const float* u1 = (const float*)d_in[0];
  const float* u2 = (const float*)d_in[1];
  const float* i1 = (const float*)d_in[2];
  const float* i2 = (const float*)d_in[3];

  // ws layout: 4 bf16 matrices (8 MB) | diag[4][NR] f32 | sums[6][NR] f32
  uint16_t* nb = (uint16_t*)d_ws;
  float* diag = (float*)((char*)d_ws + (size_t)4 * NR * DD * sizeof(uint16_t));
  float* sums = diag + 4 * NR;
  float* out = (float*)d_out;

  k_normalize<<<NR * 4 / 4, 256, 0, stream>>>(u1, u2, i1, i2, nb, diag, sums, out);
  k_gram<<<4160, 256, 0, stream>>>(nb, sums);
  k_finalize<<<256, 256, 0, stream>>>(nb, diag, sums, out);
}

// Round 5
// 215.214 us; speedup vs baseline: 2.5475x; 2.5475x over previous
//
#include <hip/hip_runtime.h>
#include <stdint.h>

#define NR 8192
#define DD 128

typedef __attribute__((ext_vector_type(8))) short bf16x8;
typedef __attribute__((ext_vector_type(4))) float f32x4;

#ifdef __has_builtin
#if __has_builtin(__builtin_amdgcn_exp2f)
#define EXP2F __builtin_amdgcn_exp2f
#endif
#endif
#ifndef EXP2F
#define EXP2F exp2f
#endif

// exp(10*x) == exp2(x * 10/ln2).  The 10/ln2 is folded into the stored bf16:
// nb = round_bf16( sqrt(10/ln2) * normalized ), so every pairwise product
// (MFMA dot, p0 elementwise, diag) is already the exp2 argument.
#define SQK 3.79828255f   // sqrt(10/ln2)

__device__ __forceinline__ uint16_t f2bf_rne(float f) {
  uint32_t u = __float_as_uint(f);
  u += 0x7FFFu + ((u >> 16) & 1u);
  return (uint16_t)(u >> 16);
}
__device__ __forceinline__ float bf2f(uint16_t h) {
  return __uint_as_float(((uint32_t)h) << 16);
}

// ---------------------------------------------------------------------------
// K1: row L2-normalize (fp32 math), emit bf16 copies scaled by SQK, plus
// diag = sum(stored^2). Also zeroes the 6 row-sum arrays and d_out.
// ---------------------------------------------------------------------------
__global__ __launch_bounds__(256) void k_normalize(
    const float* __restrict__ u1, const float* __restrict__ u2,
    const float* __restrict__ i1, const float* __restrict__ i2,
    uint16_t* __restrict__ nb, float* __restrict__ diag,
    float* __restrict__ sums, float* __restrict__ out)
{
  int tid = threadIdx.x;
  int gid = blockIdx.x * 256 + tid;
  if (gid < 6 * NR) sums[gid] = 0.0f;
  if (gid == 0) out[0] = 0.0f;

  int w = tid >> 6, lane = tid & 63;
  int rowId = blockIdx.x * 4 + w;            // 0..32767
  int mi = rowId >> 13, r = rowId & (NR - 1);
  const float* src = (mi == 0) ? u1 : (mi == 1) ? u2 : (mi == 2) ? i1 : i2;
  const float2 v = *(const float2*)(src + (size_t)r * DD + lane * 2);
  float ss = v.x * v.x + v.y * v.y;
#pragma unroll
  for (int off = 32; off >= 1; off >>= 1) ss += __shfl_xor(ss, off, 64);
  float sc = SQK / fmaxf(sqrtf(ss), 1e-12f);
  uint16_t b0 = f2bf_rne(v.x * sc);
  uint16_t b1 = f2bf_rne(v.y * sc);
  uint16_t* dst = nb + (size_t)mi * NR * DD + (size_t)r * DD + lane * 2;
  *(uint32_t*)dst = (uint32_t)b0 | ((uint32_t)b1 << 16);
  float f0 = bf2f(b0), f1 = bf2f(b1);
  float dd = f0 * f0 + f1 * f1;
#pragma unroll
  for (int off = 32; off >= 1; off >>= 1) dd += __shfl_xor(dd, off, 64);
  if (lane == 0) diag[rowId] = dd;
}

// ---------------------------------------------------------------------------
// K2: Gram row-sums with SYMMETRY: s11/s22 Grams are symmetric, so only the
// upper-triangular 256x256 blocks are computed; off-diagonal blocks emit
// row-sums AND col-sums (col-sum j == transposed row-sum).  Work: 6 full
// Grams -> 2 full (cross s12) + 4 triangles = 4.06 equivalents (-32%).
// Per block: 4 waves x 64 rows (MR=4); 4 staged 64-col tiles, 2-phase
// double-buffered LDS pipeline, one barrier per tile.
// grid = 2*1024 (cross) + 4*528 (triangle) = 4160 blocks, XCD-chunk swizzle.
// __launch_bounds__(256,3): round 4's (256,4) capped VGPR at 64 -> ~1GB of
// scratch spill traffic (WRITE_SIZE 972MB, 5x slowdown).  3 gives 84+eps
// VGPRs spill-free (round-3-verified).
// ---------------------------------------------------------------------------
__global__ __launch_bounds__(256, 3) void k_gram(
    const uint16_t* __restrict__ nb, float* __restrict__ sums)
{
  __shared__ alignas(16) uint16_t ldsB[2][64 * DD];   // 2 x 16 KB

  // bijective XCD-chunk swizzle: 4160 = 8 * 520
  int bid = (blockIdx.x & 7) * 520 + (blockIdx.x >> 3);

  int job, rb, cb;
  if (bid < 2048) {                    // cross jobs: full 32x32 block grid
    job = (bid >= 1024) ? 3 : 0;
    int r = bid & 1023;
    rb = r >> 5;
    cb = r & 31;
  } else {                             // symmetric jobs: upper triangle
    int s = bid - 2048;
    int grp = s / 528;                 // 0..3
    int idx = s - grp * 528;
    const int sjob[4] = {1, 2, 4, 5};
    job = sjob[grp];
    // triangular decode: C(r) = r*(65-r)/2 blocks before row r
    int r = (int)((65.0f - sqrtf(4225.0f - 8.0f * (float)idx)) * 0.5f);
    r = (r < 0) ? 0 : (r > 31 ? 31 : r);
    while (r > 0 && (r * (65 - r)) / 2 > idx) --r;
    while (r < 31 && ((r + 1) * (64 - r)) / 2 <= idx) ++r;
    rb = r;
    cb = r + (idx - (r * (65 - r)) / 2);
  }
  bool needCol = (job != 0 && job != 3) && (rb != cb);

  // job -> (A matrix, B matrix, output slot): 0:(u1,u2)->s12u 1:(u1,u1)->s11u
  // 2:(u2,u2)->s22u 3:(i1,i2)->s12i 4:(i1,i1)->s11i 5:(i2,i2)->s22i
  const int ja[6] = {0, 0, 1, 2, 2, 3};
  const int jb[6] = {1, 0, 1, 3, 2, 3};
  const uint16_t* A = nb + (size_t)ja[job] * NR * DD;
  const uint16_t* B = nb + (size_t)jb[job] * NR * DD;
  float* out = sums + job * NR;

  int tid = threadIdx.x, w = tid >> 6, lane = tid & 63;
  int l15 = lane & 15, lg = lane >> 4;
  int rowBase = rb * 256 + w * 64;
  int colBase = cb * 256;

  const char* Bb = (const char*)B;
  char* buf0 = (char*)&ldsB[0][0];
  char* buf1 = (char*)&ldsB[1][0];

  // stage one 64-col B tile (16KB): linear LDS dest, inverse-swizzled global
  // source (rule #21)
#define STAGE(dst, jt)                                                        \
  {                                                                           \
    const char* tbase = Bb + (size_t)(colBase + (jt) * 64) * 256;             \
    _Pragma("unroll")                                                         \
    for (int it = 0; it < 4; ++it) {                                          \
      int dbase = w * 4096 + it * 1024;                                       \
      int doff = dbase + lane * 16;                                           \
      int soff = doff ^ (((doff >> 8) & 7) << 4);                             \
      __builtin_amdgcn_global_load_lds(                                       \
          (const __attribute__((address_space(1))) void*)(tbase + soff),      \
          (__attribute__((address_space(3))) void*)((dst) + dbase),           \
          16, 0, 0);                                                          \
    }                                                                         \
  }

  STAGE(buf0, 0);          // prologue; A-frag loads fly under it

  bf16x8 af[4][4];
#pragma unroll
  for (int m = 0; m < 4; ++m) {
    const uint16_t* ap = A + (size_t)(rowBase + m * 16 + l15) * DD + lg * 8;
#pragma unroll
    for (int ks = 0; ks < 4; ++ks)
      af[m][ks] = *(const bf16x8*)(ap + ks * 32);
  }

  float racc[4][4];
#pragma unroll
  for (int m = 0; m < 4; ++m)
#pragma unroll
    for (int j = 0; j < 4; ++j) racc[m][j] = 0.0f;

  __syncthreads();   // tile 0 staged (implicit vmcnt(0) drain)

  for (int jt = 0; jt < 4; ++jt) {
    char* curb = (jt & 1) ? buf1 : buf0;
    char* nxtb = (jt & 1) ? buf0 : buf1;
    if (jt < 3) STAGE(nxtb, jt + 1);   // in-flight under compute

    if (needCol) {
      float csum[4];
#pragma unroll
      for (int c = 0; c < 4; ++c) {
        int r = c * 16 + l15;
        int rbyte = r * 256;
        int swz = (r & 7) << 4;
        bf16x8 bfr[4];
#pragma unroll
        for (int ks = 0; ks < 4; ++ks) {
          int L = rbyte + ks * 64 + lg * 16;
          bfr[ks] = *(const bf16x8*)(curb + (L ^ swz));
        }
        float cacc = 0.0f;
#pragma unroll
        for (int m = 0; m < 4; ++m) {
          f32x4 acc = {0.0f, 0.0f, 0.0f, 0.0f};
#pragma unroll
          for (int ks = 0; ks < 4; ++ks)
            acc = __builtin_amdgcn_mfma_f32_16x16x32_bf16(af[m][ks], bfr[ks], acc, 0, 0, 0);
#pragma unroll
          for (int j = 0; j < 4; ++j) {
            float v = EXP2F(acc[j]);
            racc[m][j] += v;         // row (rowBase+m*16+lg*4+j)
            cacc += v;               // col (colBase+jt*64+c*16+l15)
          }
        }
        csum[c] = cacc;
      }
      // col-sums: reduce over lg (rows), one atomic per col
#pragma unroll
      for (int c = 0; c < 4; ++c) {
        float v = csum[c];
        v += __shfl_xor(v, 16, 64);
        v += __shfl_xor(v, 32, 64);
        if (lg == 0) atomicAdd(&out[colBase + jt * 64 + c * 16 + l15], v);
      }
    } else {
#pragma unroll
      for (int c = 0; c < 4; ++c) {
        int r = c * 16 + l15;
        int rbyte = r * 256;
        int swz = (r & 7) << 4;
        bf16x8 bfr[4];
#pragma unroll
        for (int ks = 0; ks < 4; ++ks) {
          int L = rbyte + ks * 64 + lg * 16;
          bfr[ks] = *(const bf16x8*)(curb + (L ^ swz));
        }
#pragma unroll
        for (int m = 0; m < 4; ++m) {
          f32x4 acc = {0.0f, 0.0f, 0.0f, 0.0f};
#pragma unroll
          for (int ks = 0; ks < 4; ++ks)
            acc = __builtin_amdgcn_mfma_f32_16x16x32_bf16(af[m][ks], bfr[ks], acc, 0, 0, 0);
#pragma unroll
          for (int j = 0; j < 4; ++j)
            racc[m][j] += EXP2F(acc[j]);
        }
      }
    }
    if (jt < 3) __syncthreads();       // next tile staged; cur reusable
  }

  // row-sums: reduce over the 16 lanes (cols) in each lg group
#pragma unroll
  for (int off = 1; off < 16; off <<= 1)
#pragma unroll
    for (int m = 0; m < 4; ++m)
#pragma unroll
      for (int j = 0; j < 4; ++j)
        racc[m][j] += __shfl_xor(racc[m][j], off, 64);

  if (l15 == 0) {
#pragma unroll
    for (int m = 0; m < 4; ++m)
#pragma unroll
      for (int j = 0; j < 4; ++j)
        atomicAdd(&out[rowBase + m * 16 + lg * 4 + j], racc[m][j]);
  }
#undef STAGE
}

// ---------------------------------------------------------------------------
// K3: finalize.  16 rows per wave, one atomic per BLOCK (256 total).
// loss += log(s12+s11+p0) + log(s12+s22+p0) - 2*log(p0);  out = loss/4.
// ---------------------------------------------------------------------------
__global__ __launch_bounds__(256) void k_finalize(
    const uint16_t* __restrict__ nb, const float* __restrict__ diag,
    const float* __restrict__ sums, float* __restrict__ out)
{
  __shared__ float part[4];
  int tid = threadIdx.x, w = tid >> 6, lane = tid & 63;
  int waveId = blockIdx.x * 4 + w;        // 0..1023
  float local = 0.0f;

  for (int i = 0; i < 16; ++i) {
    int rowId = waveId * 16 + i;          // 0..16383
    int p = rowId >> 13, r = rowId & (NR - 1);
    const uint16_t* n1 = nb + (size_t)(2 * p) * NR * DD + (size_t)r * DD;
    const uint16_t* n2 = n1 + (size_t)NR * DD;
    uint32_t a = *(const uint32_t*)(n1 + lane * 2);
    uint32_t b = *(const uint32_t*)(n2 + lane * 2);
    float a0 = bf2f((uint16_t)(a & 0xFFFFu)), a1 = bf2f((uint16_t)(a >> 16));
    float b0 = bf2f((uint16_t)(b & 0xFFFFu)), b1 = bf2f((uint16_t)(b >> 16));
    // values pre-scaled by SQK: product is already the exp2 argument
    float p0 = EXP2F(a0 * b0) + EXP2F(a1 * b1);
#pragma unroll
    for (int off = 32; off >= 1; off >>= 1) p0 += __shfl_xor(p0, off, 64);

    if (lane == 0) {
      const float* s12v = sums + (3 * p) * NR;
      const float* s11v = sums + (3 * p + 1) * NR;
      const float* s22v = sums + (3 * p + 2) * NR;
      float e1 = EXP2F(diag[(2 * p) * NR + r]);
      float e2 = EXP2F(diag[(2 * p + 1) * NR + r]);
      float s12 = s12v[r];
      float S1 = s12 + (s11v[r] - e1) + p0;
      float S2 = s12 + (s22v[r] - e2) + p0;
      local += logf(S1) + logf(S2) - 2.0f * logf(p0);
    }
  }
  if (lane == 0) part[w] = local;
  __syncthreads();
  if (tid == 0) {
    float t = part[0] + part[1] + part[2] + part[3];
    atomicAdd(out, 0.25f * t);
  }
}

// ---------------------------------------------------------------------------
extern "C" void kernel_launch(void* const* d_in, const int* in_sizes, int n_in,
                              void* d_out, int out_size, void* d_ws, size_t ws_size,
                              hipStream_t stream) {
  const float* u1 = (const float*)d_in[0];
  const float* u2 = (const float*)d_in[1];
  const float* i1 = (const float*)d_in[2];
  const float* i2 = (const float*)d_in[3];

  // ws layout: 4 bf16 matrices (8 MB) | diag[4][NR] f32 | sums[6][NR] f32
  uint16_t* nb = (uint16_t*)d_ws;
  float* diag = (float*)((char*)d_ws + (size_t)4 * NR * DD * sizeof(uint16_t));
  float* sums = diag + 4 * NR;
  float* out = (float*)d_out;

  k_normalize<<<NR * 4 / 4, 256, 0, stream>>>(u1, u2, i1, i2, nb, diag, sums, out);
  k_gram<<<4160, 256, 0, stream>>>(nb, sums);
  k_finalize<<<256, 256, 0, stream>>>(nb, diag, sums, out);
}

// Round 6
// 183.099 us; speedup vs baseline: 2.9944x; 1.1754x over previous
//
#include <hip/hip_runtime.h>
#include <stdint.h>

#define NR 8192
#define DD 128

typedef __attribute__((ext_vector_type(8))) short bf16x8;
typedef __attribute__((ext_vector_type(4))) float f32x4;

#ifdef __has_builtin
#if __has_builtin(__builtin_amdgcn_exp2f)
#define EXP2F __builtin_amdgcn_exp2f
#endif
#endif
#ifndef EXP2F
#define EXP2F exp2f
#endif

// exp(10*x) == exp2(x * 10/ln2).  10/ln2 is folded into the stored bf16:
// nb = round_bf16( sqrt(10/ln2) * normalized ), so every pairwise product
// (MFMA dot, p0 elementwise, diag) is already the exp2 argument.
#define SQK 3.79828255f   // sqrt(10/ln2)

__device__ __forceinline__ uint16_t f2bf_rne(float f) {
  uint32_t u = __float_as_uint(f);
  u += 0x7FFFu + ((u >> 16) & 1u);
  return (uint16_t)(u >> 16);
}
__device__ __forceinline__ float bf2f(uint16_t h) {
  return __uint_as_float(((uint32_t)h) << 16);
}

// ---------------------------------------------------------------------------
// K1: row L2-normalize (fp32), emit bf16 copies scaled by SQK, diag =
// sum(stored^2).  Also zeroes sums, d_out, and the credit scratch slab.
// ---------------------------------------------------------------------------
__global__ __launch_bounds__(256) void k_normalize(
    const float* __restrict__ u1, const float* __restrict__ u2,
    const float* __restrict__ i1, const float* __restrict__ i2,
    uint16_t* __restrict__ nb, float* __restrict__ diag,
    float* __restrict__ sums, float* __restrict__ scratch, int scrN,
    float* __restrict__ out)
{
  int tid = threadIdx.x;
  int gid = blockIdx.x * 256 + tid;
  if (gid < 6 * NR) sums[gid] = 0.0f;
  if (gid < scrN) scratch[gid] = 0.0f;     // grid covers 2.1M threads >= scrN
  if (gid == 0) out[0] = 0.0f;

  int w = tid >> 6, lane = tid & 63;
  int rowId = blockIdx.x * 4 + w;            // 0..32767
  int mi = rowId >> 13, r = rowId & (NR - 1);
  const float* src = (mi == 0) ? u1 : (mi == 1) ? u2 : (mi == 2) ? i1 : i2;
  const float2 v = *(const float2*)(src + (size_t)r * DD + lane * 2);
  float ss = v.x * v.x + v.y * v.y;
#pragma unroll
  for (int off = 32; off >= 1; off >>= 1) ss += __shfl_xor(ss, off, 64);
  float sc = SQK / fmaxf(sqrtf(ss), 1e-12f);
  uint16_t b0 = f2bf_rne(v.x * sc);
  uint16_t b1 = f2bf_rne(v.y * sc);
  uint16_t* dst = nb + (size_t)mi * NR * DD + (size_t)r * DD + lane * 2;
  *(uint32_t*)dst = (uint32_t)b0 | ((uint32_t)b1 << 16);
  float f0 = bf2f(b0), f1 = bf2f(b1);
  float dd = f0 * f0 + f1 * f1;
#pragma unroll
  for (int off = 32; off >= 1; off >>= 1) dd += __shfl_xor(dd, off, 64);
  if (lane == 0) diag[rowId] = dd;
}

// ---------------------------------------------------------------------------
// K2: Gram row-sums with symmetry via ROW PANELS + atomic-free col credits.
// Cross jobs (s12): full grid, 32 rb x 8 chunks x 16 tiles (64 cols each).
// Symmetric jobs (s11/s22): panel rb covers cols [256rb, 8192) in 16-tile
// chunks; tiles right of the diagonal block (ct >= 4rb+4) also emit per-col
// credits = transposed row-sums.  Credits: wave partials -> ldsCol (2KB,
// double-buffered) -> ONE designated wave plain-stores 64 f32 to
// scratch[sj][rb][col] (unique writer per (job,panel,tile): no atomics).
// Row-sums: ~4 atomics/row (round-3 level; round 5's 1.57M device atomics
// cost ~90us of coherent-fabric RMW traffic - 274MB WRITE_SIZE).
// grid = 512 cross + 576 symm = 1088 = 8*136 blocks, XCD-chunk swizzle.
// ---------------------------------------------------------------------------
__global__ __launch_bounds__(256, 3) void k_gram(
    const uint16_t* __restrict__ nb, float* __restrict__ sums,
    float* __restrict__ scratch, int useScratch)
{
  __shared__ alignas(16) uint16_t ldsB[2][64 * DD];   // 2 x 16 KB
  __shared__ float ldsCol[2][4][64];                  // 2 KB credit buffer

  // bijective XCD-chunk swizzle: 1088 = 8 * 136
  int bid = (blockIdx.x & 7) * 136 + (blockIdx.x >> 3);

  int job, rb, ct0, nt, sj = 0;
  bool isSym;
  if (bid < 512) {                       // cross jobs: full 128-tile rows
    isSym = false;
    job = (bid >= 256) ? 3 : 0;
    int r = bid & 255;
    rb = r >> 3;                         // 0..31
    ct0 = (r & 7) * 16;                  // 0..112
    nt = 16;
  } else {                               // symmetric jobs: triangle panels
    isSym = true;
    int s = bid - 512;
    sj = s / 144;                        // 0..3
    int idx = s - sj * 144;
    const int sjobs[4] = {1, 2, 4, 5};
    job = sjobs[sj];
    int base = 0;
    rb = 0;
    for (;;) {                           // uniform scalar scan, <=32 iters
      int c = (35 - rb) >> 2;            // ceil((32-rb)/4) chunks in panel rb
      if (idx < base + c) break;
      base += c;
      ++rb;
    }
    int ch = idx - base;
    ct0 = 4 * rb + ch * 16;
    int rem = 128 - 4 * rb - ch * 16;
    nt = rem < 16 ? rem : 16;            // 4..16 tiles
  }
  int credMin = 4 * rb + 4;              // symm tiles >= this emit credits

  // job -> (A,B,out): 0:(u1,u2) 1:(u1,u1) 2:(u2,u2) 3:(i1,i2) 4:(i1,i1) 5:(i2,i2)
  const int ja[6] = {0, 0, 1, 2, 2, 3};
  const int jb[6] = {1, 0, 1, 3, 2, 3};
  const uint16_t* A = nb + (size_t)ja[job] * NR * DD;
  const uint16_t* B = nb + (size_t)jb[job] * NR * DD;
  float* out = sums + job * NR;

  int tid = threadIdx.x, w = tid >> 6, lane = tid & 63;
  int l15 = lane & 15, lg = lane >> 4;
  int rowBase = rb * 256 + w * 64;

  const char* Bb = (const char*)B;
  char* buf0 = (char*)&ldsB[0][0];
  char* buf1 = (char*)&ldsB[1][0];

  // stage one 64-col tile (16KB): linear LDS dest, inverse-swizzled source
#define STAGE(dst, jt)                                                        \
  {                                                                           \
    const char* tbase = Bb + (size_t)(ct0 + (jt)) * 16384;                    \
    _Pragma("unroll")                                                         \
    for (int it = 0; it < 4; ++it) {                                          \
      int dbase = w * 4096 + it * 1024;                                       \
      int doff = dbase + lane * 16;                                           \
      int soff = doff ^ (((doff >> 8) & 7) << 4);                             \
      __builtin_amdgcn_global_load_lds(                                       \
          (const __attribute__((address_space(1))) void*)(tbase + soff),      \
          (__attribute__((address_space(3))) void*)((dst) + dbase),           \
          16, 0, 0);                                                          \
    }                                                                         \
  }

#define FLUSH(pt)                                                             \
  {                                                                           \
    float fv = ldsCol[(pt) & 1][0][lane] + ldsCol[(pt) & 1][1][lane] +        \
               ldsCol[(pt) & 1][2][lane] + ldsCol[(pt) & 1][3][lane];         \
    int fcol = (ct0 + (pt)) * 64 + lane;                                      \
    if (useScratch)                                                           \
      scratch[(size_t)(sj * 32 + rb) * NR + fcol] = fv;                       \
    else                                                                      \
      atomicAdd(&out[fcol], fv);                                              \
  }

  STAGE(buf0, 0);          // prologue; A-frag loads fly under it

  bf16x8 af[4][4];
#pragma unroll
  for (int m = 0; m < 4; ++m) {
    const uint16_t* ap = A + (size_t)(rowBase + m * 16 + l15) * DD + lg * 8;
#pragma unroll
    for (int ks = 0; ks < 4; ++ks)
      af[m][ks] = *(const bf16x8*)(ap + ks * 32);
  }

  float racc[4][4];
#pragma unroll
  for (int m = 0; m < 4; ++m)
#pragma unroll
    for (int j = 0; j < 4; ++j) racc[m][j] = 0.0f;

  __syncthreads();   // tile 0 staged (implicit vmcnt(0) drain)

  for (int jt = 0; jt < nt; ++jt) {
    char* curb = (jt & 1) ? buf1 : buf0;
    char* nxtb = (jt & 1) ? buf0 : buf1;
    if (jt < nt - 1) STAGE(nxtb, jt + 1);   // in-flight under compute

    bool cr = isSym && (ct0 + jt) >= credMin;
    if (cr) {
#pragma unroll
      for (int c = 0; c < 4; ++c) {
        int r = c * 16 + l15;
        int rbyte = r * 256;
        int swz = (r & 7) << 4;
        bf16x8 bfr[4];
#pragma unroll
        for (int ks = 0; ks < 4; ++ks) {
          int L = rbyte + ks * 64 + lg * 16;
          bfr[ks] = *(const bf16x8*)(curb + (L ^ swz));
        }
        float cacc = 0.0f;
#pragma unroll
        for (int m = 0; m < 4; ++m) {
          f32x4 acc = {0.0f, 0.0f, 0.0f, 0.0f};
#pragma unroll
          for (int ks = 0; ks < 4; ++ks)
            acc = __builtin_amdgcn_mfma_f32_16x16x32_bf16(af[m][ks], bfr[ks], acc, 0, 0, 0);
#pragma unroll
          for (int j = 0; j < 4; ++j) {
            float v = EXP2F(acc[j]);
            racc[m][j] += v;         // row (rowBase+m*16+lg*4+j)
            cacc += v;               // col ((ct0+jt)*64 + c*16+l15)
          }
        }
        // reduce this wave's 64-row partial across lg groups
        cacc += __shfl_xor(cacc, 16, 64);
        cacc += __shfl_xor(cacc, 32, 64);
        if (lg == 0) ldsCol[jt & 1][w][c * 16 + l15] = cacc;
      }
    } else {
#pragma unroll
      for (int c = 0; c < 4; ++c) {
        int r = c * 16 + l15;
        int rbyte = r * 256;
        int swz = (r & 7) << 4;
        bf16x8 bfr[4];
#pragma unroll
        for (int ks = 0; ks < 4; ++ks) {
          int L = rbyte + ks * 64 + lg * 16;
          bfr[ks] = *(const bf16x8*)(curb + (L ^ swz));
        }
#pragma unroll
        for (int m = 0; m < 4; ++m) {
          f32x4 acc = {0.0f, 0.0f, 0.0f, 0.0f};
#pragma unroll
          for (int ks = 0; ks < 4; ++ks)
            acc = __builtin_amdgcn_mfma_f32_16x16x32_bf16(af[m][ks], bfr[ks], acc, 0, 0, 0);
#pragma unroll
          for (int j = 0; j < 4; ++j)
            racc[m][j] += EXP2F(acc[j]);
        }
      }
    }

    // flush PREVIOUS tile's credits (its ldsCol buffer is stable: written
    // before barrier jt-1, not reused until after barrier jt)
    if (jt > 0 && isSym && (ct0 + jt - 1) >= credMin && w == ((jt - 1) & 3))
      FLUSH(jt - 1);

    __syncthreads();     // next tile staged; cur buffers reusable
  }
  // post-loop: flush last tile (loop's final barrier ordered its writes)
  if (isSym && (ct0 + nt - 1) >= credMin && w == ((nt - 1) & 3))
    FLUSH(nt - 1);

  // row-sums: reduce over the 16 lanes (cols) in each lg group
#pragma unroll
  for (int off = 1; off < 16; off <<= 1)
#pragma unroll
    for (int m = 0; m < 4; ++m)
#pragma unroll
      for (int j = 0; j < 4; ++j)
        racc[m][j] += __shfl_xor(racc[m][j], off, 64);

  if (l15 == 0) {
#pragma unroll
    for (int m = 0; m < 4; ++m)
#pragma unroll
      for (int j = 0; j < 4; ++j)
        atomicAdd(&out[rowBase + m * 16 + lg * 4 + j], racc[m][j]);
  }
#undef STAGE
#undef FLUSH
}

// ---------------------------------------------------------------------------
// K2b: reduce credit scratch [4][32][NR] -> credit [4][NR] (coalesced).
// ---------------------------------------------------------------------------
__global__ __launch_bounds__(256) void k_credit(
    const float* __restrict__ scratch, float* __restrict__ credit)
{
  int gid = blockIdx.x * 256 + threadIdx.x;   // 0..32767
  int s = gid >> 13, c = gid & (NR - 1);
  float t = 0.0f;
#pragma unroll 8
  for (int rb = 0; rb < 32; ++rb)
    t += scratch[(size_t)(s * 32 + rb) * NR + c];
  credit[s * NR + c] = t;
}

// ---------------------------------------------------------------------------
// K3: finalize.  16 rows per wave, one atomic per BLOCK (256 total).
// s11/s22 = atomic row-part + credit part;  loss per row as before.
// ---------------------------------------------------------------------------
__global__ __launch_bounds__(256) void k_finalize(
    const uint16_t* __restrict__ nb, const float* __restrict__ diag,
    const float* __restrict__ sums, const float* __restrict__ credit,
    int useScratch, float* __restrict__ out)
{
  __shared__ float part[4];
  int tid = threadIdx.x, w = tid >> 6, lane = tid & 63;
  int waveId = blockIdx.x * 4 + w;        // 0..1023
  float local = 0.0f;

  for (int i = 0; i < 16; ++i) {
    int rowId = waveId * 16 + i;          // 0..16383
    int p = rowId >> 13, r = rowId & (NR - 1);
    const uint16_t* n1 = nb + (size_t)(2 * p) * NR * DD + (size_t)r * DD;
    const uint16_t* n2 = n1 + (size_t)NR * DD;
    uint32_t a = *(const uint32_t*)(n1 + lane * 2);
    uint32_t b = *(const uint32_t*)(n2 + lane * 2);
    float a0 = bf2f((uint16_t)(a & 0xFFFFu)), a1 = bf2f((uint16_t)(a >> 16));
    float b0 = bf2f((uint16_t)(b & 0xFFFFu)), b1 = bf2f((uint16_t)(b >> 16));
    float p0 = EXP2F(a0 * b0) + EXP2F(a1 * b1);
#pragma unroll
    for (int off = 32; off >= 1; off >>= 1) p0 += __shfl_xor(p0, off, 64);

    if (lane == 0) {
      const float* s12v = sums + (3 * p) * NR;
      const float* s11v = sums + (3 * p + 1) * NR;
      const float* s22v = sums + (3 * p + 2) * NR;
      float cA = useScratch ? credit[(2 * p) * NR + r] : 0.0f;
      float cB = useScratch ? credit[(2 * p + 1) * NR + r] : 0.0f;
      float e1 = EXP2F(diag[(2 * p) * NR + r]);
      float e2 = EXP2F(diag[(2 * p + 1) * NR + r]);
      float s12 = s12v[r];
      float S1 = s12 + (s11v[r] + cA - e1) + p0;
      float S2 = s12 + (s22v[r] + cB - e2) + p0;
      local += logf(S1) + logf(S2) - 2.0f * logf(p0);
    }
  }
  if (lane == 0) part[w] = local;
  __syncthreads();
  if (tid == 0) {
    float t = part[0] + part[1] + part[2] + part[3];
    atomicAdd(out, 0.25f * t);
  }
}

// ---------------------------------------------------------------------------
extern "C" void kernel_launch(void* const* d_in, const int* in_sizes, int n_in,
                              void* d_out, int out_size, void* d_ws, size_t ws_size,
                              hipStream_t stream) {
  const float* u1 = (const float*)d_in[0];
  const float* u2 = (const float*)d_in[1];
  const float* i1 = (const float*)d_in[2];
  const float* i2 = (const float*)d_in[3];

  // ws: nb 8MB | diag[4][NR] | sums[6][NR] | scratch[4][32][NR] 4MB | credit[4][NR]
  uint16_t* nb = (uint16_t*)d_ws;
  float* diag = (float*)((char*)d_ws + (size_t)4 * NR * DD * sizeof(uint16_t));
  float* sums = diag + 4 * NR;
  float* scratch = sums + 6 * NR;
  float* credit = scratch + (size_t)4 * 32 * NR;
  float* out = (float*)d_out;

  size_t need = (size_t)((char*)(credit + 4 * NR) - (char*)d_ws);
  int useScratch = (ws_size >= need) ? 1 : 0;
  int scrN = useScratch ? 4 * 32 * NR : 0;
  if (!useScratch) { scratch = sums; credit = sums; }  // valid dummies, unused

  k_normalize<<<NR * 4 / 4, 256, 0, stream>>>(u1, u2, i1, i2, nb, diag, sums,
                                              scratch, scrN, out);
  k_gram<<<1088, 256, 0, stream>>>(nb, sums, scratch, useScratch);
  if (useScratch) k_credit<<<128, 256, 0, stream>>>(scratch, credit);
  k_finalize<<<256, 256, 0, stream>>>(nb, diag, sums, credit, useScratch, out);
}

// Round 8
// 125.892 us; speedup vs baseline: 4.3550x; 1.4544x over previous
//
#include <hip/hip_runtime.h>
#include <stdint.h>

#define NR 8192
#define DD 128

typedef __attribute__((ext_vector_type(8))) short bf16x8;
typedef __attribute__((ext_vector_type(4))) float f32x4;

#ifdef __has_builtin
#if __has_builtin(__builtin_amdgcn_exp2f)
#define EXP2F __builtin_amdgcn_exp2f
#endif
#endif
#ifndef EXP2F
#define EXP2F exp2f
#endif

// exp(10*x) == exp2(x * 10/ln2).  10/ln2 is folded into the stored bf16:
// nb = round_bf16( sqrt(10/ln2) * normalized ), so every pairwise product
// (MFMA dot, p0 elementwise, diag) is already the exp2 argument.
#define SQK 3.79828255f   // sqrt(10/ln2)

__device__ __forceinline__ uint16_t f2bf_rne(float f) {
  uint32_t u = __float_as_uint(f);
  u += 0x7FFFu + ((u >> 16) & 1u);
  return (uint16_t)(u >> 16);
}
__device__ __forceinline__ float bf2f(uint16_t h) {
  return __uint_as_float(((uint32_t)h) << 16);
}

// ---------------------------------------------------------------------------
// K1: row L2-normalize (fp32), emit bf16 copies scaled by SQK, diag =
// sum(stored^2).  Also zeroes sums and d_out.  One wave per row.
// ---------------------------------------------------------------------------
__global__ __launch_bounds__(256) void k_normalize(
    const float* __restrict__ u1, const float* __restrict__ u2,
    const float* __restrict__ i1, const float* __restrict__ i2,
    uint16_t* __restrict__ nb, float* __restrict__ diag,
    float* __restrict__ sums, float* __restrict__ out)
{
  int tid = threadIdx.x;
  int gid = blockIdx.x * 256 + tid;
  if (gid < 6 * NR) sums[gid] = 0.0f;
  if (gid == 0) out[0] = 0.0f;

  int w = tid >> 6, lane = tid & 63;
  int rowId = blockIdx.x * 4 + w;            // 0..32767
  int mi = rowId >> 13, r = rowId & (NR - 1);
  const float* src = (mi == 0) ? u1 : (mi == 1) ? u2 : (mi == 2) ? i1 : i2;
  const float2 v = *(const float2*)(src + (size_t)r * DD + lane * 2);
  float ss = v.x * v.x + v.y * v.y;
#pragma unroll
  for (int off = 32; off >= 1; off >>= 1) ss += __shfl_xor(ss, off, 64);
  float sc = SQK / fmaxf(sqrtf(ss), 1e-12f);
  uint16_t b0 = f2bf_rne(v.x * sc);
  uint16_t b1 = f2bf_rne(v.y * sc);
  uint16_t* dst = nb + (size_t)mi * NR * DD + (size_t)r * DD + lane * 2;
  *(uint32_t*)dst = (uint32_t)b0 | ((uint32_t)b1 << 16);
  float f0 = bf2f(b0), f1 = bf2f(b1);
  float dd = f0 * f0 + f1 * f1;
#pragma unroll
  for (int off = 32; off >= 1; off >>= 1) dd += __shfl_xor(dd, off, 64);
  if (lane == 0) diag[rowId] = dd;
}

// ---------------------------------------------------------------------------
// K2: Gram row-sums — round-3 uniform structure (6 full Grams, 768 blocks,
// 32 tiles/block) + T3/T4 counted-vmcnt pipeline:
//   TRIPLE-buffered LDS (3 x 16 KB), loop = { STAGE(t+1); s_waitcnt vmcnt(4);
//   s_barrier; COMPUTE(t) } — never vmcnt(0) in the main loop.
// Per-wave vmcnt(4) (4 loads just issued for t+1) guarantees this wave's
// stage(t) loads retired; the raw barrier then makes all waves' stage(t)
// visible.  Triple-buffer removes the WAW hazard (one barrier/iter bounds
// inter-wave drift <1 iter; stager of (t+2)%3 never touches reader's t%3).
// Replaces __syncthreads' structural vmcnt(0)+lgkmcnt(0) drain (m97 stall;
// m218 counted-vmcnt = +38-73%).
// NOTE: no pointer ARRAY of LDS buffers (addrspacecast static-init is
// unsupported on gfx950) — single base pointer + idx*16384 arithmetic.
// ---------------------------------------------------------------------------
__global__ __launch_bounds__(256, 3) void k_gram(
    const uint16_t* __restrict__ nb, float* __restrict__ sums)
{
  __shared__ alignas(16) uint16_t ldsB[3][64 * DD];   // 3 x 16 KB

  // bijective XCD-chunk swizzle: XCD k gets contiguous ids [k*96,(k+1)*96)
  int bid = (blockIdx.x & 7) * 96 + (blockIdx.x >> 3);
  int job = bid >> 7;          // 128 blocks per job
  int rem = bid & 127;
  int rb = rem >> 2;           // row-block 0..31 (256 rows each)
  int cs = rem & 3;            // col-chunk 0..3  (2048 cols each)
  const int ja[6] = {0, 0, 1, 2, 2, 3};
  const int jb[6] = {1, 0, 1, 3, 2, 3};
  const uint16_t* A = nb + (size_t)ja[job] * NR * DD;
  const uint16_t* B = nb + (size_t)jb[job] * NR * DD;
  float* out = sums + job * NR;

  int tid = threadIdx.x, w = tid >> 6, lane = tid & 63;
  int l15 = lane & 15, lg = lane >> 4;
  int rowBase = rb * 256 + w * 64;

  const char* Bb = (const char*)B;
  char* ldsbase = (char*)&ldsB[0][0];
  int jstart = cs * 2048;

  // stage one 64-col B tile (16KB): linear LDS dest, inverse-swizzled global
  // source (rule #21); 4 global_load_lds_dwordx4 per wave.
#define STAGE(dst, jt)                                                        \
  {                                                                           \
    const char* tbase = Bb + (size_t)(jstart + (jt) * 64) * 256;              \
    _Pragma("unroll")                                                         \
    for (int it = 0; it < 4; ++it) {                                          \
      int dbase = w * 4096 + it * 1024;                                       \
      int doff = dbase + lane * 16;                                           \
      int soff = doff ^ (((doff >> 8) & 7) << 4);                             \
      __builtin_amdgcn_global_load_lds(                                       \
          (const __attribute__((address_space(1))) void*)(tbase + soff),      \
          (__attribute__((address_space(3))) void*)((dst) + dbase),           \
          16, 0, 0);                                                          \
    }                                                                         \
  }

#define COMPUTE(bufc)                                                         \
  {                                                                           \
    _Pragma("unroll")                                                         \
    for (int c = 0; c < 4; ++c) {                                             \
      int r = c * 16 + l15;                                                   \
      int rbyte = r * 256;                                                    \
      int swz = (r & 7) << 4;                                                 \
      bf16x8 bfr[4];                                                          \
      _Pragma("unroll")                                                       \
      for (int ks = 0; ks < 4; ++ks) {                                        \
        int L = rbyte + ks * 64 + lg * 16;                                    \
        bfr[ks] = *(const bf16x8*)((bufc) + (L ^ swz));                       \
      }                                                                       \
      _Pragma("unroll")                                                       \
      for (int m = 0; m < 4; ++m) {                                           \
        f32x4 acc = {0.0f, 0.0f, 0.0f, 0.0f};                                 \
        _Pragma("unroll")                                                     \
        for (int ks = 0; ks < 4; ++ks)                                        \
          acc = __builtin_amdgcn_mfma_f32_16x16x32_bf16(af[m][ks], bfr[ks],   \
                                                        acc, 0, 0, 0);        \
        _Pragma("unroll")                                                     \
        for (int j = 0; j < 4; ++j)                                           \
          racc[m][j] += EXP2F(acc[j]);                                        \
      }                                                                       \
    }                                                                         \
  }

  // prologue: stage tile 0; A-frag loads fly under it; one full drain.
  STAGE(ldsbase, 0);

  bf16x8 af[4][4];
#pragma unroll
  for (int m = 0; m < 4; ++m) {
    const uint16_t* ap = A + (size_t)(rowBase + m * 16 + l15) * DD + lg * 8;
#pragma unroll
    for (int ks = 0; ks < 4; ++ks)
      af[m][ks] = *(const bf16x8*)(ap + ks * 32);
  }

  float racc[4][4];
#pragma unroll
  for (int m = 0; m < 4; ++m)
#pragma unroll
    for (int j = 0; j < 4; ++j) racc[m][j] = 0.0f;

  asm volatile("s_waitcnt vmcnt(0)" ::: "memory");
  __builtin_amdgcn_s_barrier();
  __builtin_amdgcn_sched_barrier(0);

  // main loop: counted-vmcnt pipeline, ONE raw barrier per tile
  int cur = 0;
  for (int jt = 0; jt < 31; ++jt) {
    int nxt = cur + 1; if (nxt == 3) nxt = 0;
    STAGE(ldsbase + nxt * 16384, jt + 1);  // 4 loads issued, stay in flight
    __builtin_amdgcn_sched_barrier(0);
    asm volatile("s_waitcnt vmcnt(4)" ::: "memory");  // stage(jt) retired
    __builtin_amdgcn_s_barrier();                     // ...in ALL waves
    __builtin_amdgcn_sched_barrier(0);
    COMPUTE(ldsbase + cur * 16384);
    cur = nxt;
  }
  // epilogue: tile 31
  __builtin_amdgcn_sched_barrier(0);
  asm volatile("s_waitcnt vmcnt(0)" ::: "memory");
  __builtin_amdgcn_s_barrier();
  __builtin_amdgcn_sched_barrier(0);
  COMPUTE(ldsbase + cur * 16384);

  // row-sums: reduce over the 16 lanes (cols) in each lg group
#pragma unroll
  for (int off = 1; off < 16; off <<= 1)
#pragma unroll
    for (int m = 0; m < 4; ++m)
#pragma unroll
      for (int j = 0; j < 4; ++j)
        racc[m][j] += __shfl_xor(racc[m][j], off, 64);

  if (l15 == 0) {
#pragma unroll
    for (int m = 0; m < 4; ++m)
#pragma unroll
      for (int j = 0; j < 4; ++j)
        atomicAdd(&out[rowBase + m * 16 + lg * 4 + j], racc[m][j]);
  }
#undef STAGE
#undef COMPUTE
}

// ---------------------------------------------------------------------------
// K3: finalize.  16 rows per wave, one atomic per BLOCK (256 total).
// loss += log(s12+s11+p0) + log(s12+s22+p0) - 2*log(p0);  out = loss/4.
// ---------------------------------------------------------------------------
__global__ __launch_bounds__(256) void k_finalize(
    const uint16_t* __restrict__ nb, const float* __restrict__ diag,
    const float* __restrict__ sums, float* __restrict__ out)
{
  __shared__ float part[4];
  int tid = threadIdx.x, w = tid >> 6, lane = tid & 63;
  int waveId = blockIdx.x * 4 + w;        // 0..1023
  float local = 0.0f;

  for (int i = 0; i < 16; ++i) {
    int rowId = waveId * 16 + i;          // 0..16383
    int p = rowId >> 13, r = rowId & (NR - 1);
    const uint16_t* n1 = nb + (size_t)(2 * p) * NR * DD + (size_t)r * DD;
    const uint16_t* n2 = n1 + (size_t)NR * DD;
    uint32_t a = *(const uint32_t*)(n1 + lane * 2);
    uint32_t b = *(const uint32_t*)(n2 + lane * 2);
    float a0 = bf2f((uint16_t)(a & 0xFFFFu)), a1 = bf2f((uint16_t)(a >> 16));
    float b0 = bf2f((uint16_t)(b & 0xFFFFu)), b1 = bf2f((uint16_t)(b >> 16));
    // values pre-scaled by SQK: product is already the exp2 argument
    float p0 = EXP2F(a0 * b0) + EXP2F(a1 * b1);
#pragma unroll
    for (int off = 32; off >= 1; off >>= 1) p0 += __shfl_xor(p0, off, 64);

    if (lane == 0) {
      const float* s12v = sums + (3 * p) * NR;
      const float* s11v = sums + (3 * p + 1) * NR;
      const float* s22v = sums + (3 * p + 2) * NR;
      float e1 = EXP2F(diag[(2 * p) * NR + r]);
      float e2 = EXP2F(diag[(2 * p + 1) * NR + r]);
      float s12 = s12v[r];
      float S1 = s12 + (s11v[r] - e1) + p0;
      float S2 = s12 + (s22v[r] - e2) + p0;
      local += logf(S1) + logf(S2) - 2.0f * logf(p0);
    }
  }
  if (lane == 0) part[w] = local;
  __syncthreads();
  if (tid == 0) {
    float t = part[0] + part[1] + part[2] + part[3];
    atomicAdd(out, 0.25f * t);
  }
}

// ---------------------------------------------------------------------------
extern "C" void kernel_launch(void* const* d_in, const int* in_sizes, int n_in,
                              void* d_out, int out_size, void* d_ws, size_t ws_size,
                              hipStream_t stream) {
  const float* u1 = (const float*)d_in[0];
  const float* u2 = (const float*)d_in[1];
  const float* i1 = (const float*)d_in[2];
  const float* i2 = (const float*)d_in[3];

  // ws layout: 4 bf16 matrices (8 MB) | diag[4][NR] f32 | sums[6][NR] f32
  uint16_t* nb = (uint16_t*)d_ws;
  float* diag = (float*)((char*)d_ws + (size_t)4 * NR * DD * sizeof(uint16_t));
  float* sums = diag + 4 * NR;
  float* out = (float*)d_out;

  k_normalize<<<NR * 4 / 4, 256, 0, stream>>>(u1, u2, i1, i2, nb, diag, sums, out);
  k_gram<<<768, 256, 0, stream>>>(nb, sums);
  k_finalize<<<256, 256, 0, stream>>>(nb, diag, sums, out);
}